// Round 4
// baseline (733.416 us; speedup 1.0000x reference)
//
#include <hip/hip_runtime.h>

typedef unsigned short u16;
typedef unsigned int u32;
typedef __attribute__((ext_vector_type(8))) __bf16 bf16x8;
typedef __attribute__((ext_vector_type(16))) float f32x16;

#define NN 8192
#define IND 512
#define DD 256
// ln(1 + 2^-9): folded into exp so that bf16-truncation of P is unbiased
#define LN_K 0.00195122595f

__device__ __forceinline__ void gl_lds16(const void* g, void* l) {
  __builtin_amdgcn_global_load_lds((const __attribute__((address_space(1))) void*)g,
                                   (__attribute__((address_space(3))) void*)l, 16, 0, 0);
}
__device__ __forceinline__ u16 bf16_rne(float x) {
  u32 u = __float_as_uint(x);
  u += 0x7FFF + ((u >> 16) & 1);
  return (u16)(u >> 16);
}

// ---------------- kernel 0a: W fp32 [512,256] -> WT bf16 [256,512], x3 -----
// Coalesced reads (thread = n, k in a short loop), 16B packed store per thread.
__global__ __launch_bounds__(256) void wt_transpose(const float* __restrict__ Wq,
                                                    const float* __restrict__ Wk,
                                                    const float* __restrict__ Wv,
                                                    u16* __restrict__ WT) {
  const int o = blockIdx.y;
  const int k0 = blockIdx.x * 8;  // 64 blocks cover k<512
  const int n = threadIdx.x;
  const float* W = (o == 0) ? Wq : ((o == 1) ? Wk : Wv);
  u32 pk[4];
#pragma unroll
  for (int g = 0; g < 4; ++g) {
    const float a = W[(size_t)(k0 + 2 * g) * DD + n];      // coalesced across n
    const float b = W[(size_t)(k0 + 2 * g + 1) * DD + n];  // coalesced across n
    pk[g] = (u32)bf16_rne(a) | ((u32)bf16_rne(b) << 16);
  }
  *(uint4*)(WT + (size_t)o * (DD * IND) + (size_t)n * IND + k0) =
      make_uint4(pk[0], pk[1], pk[2], pk[3]);
}

// ---------------- kernel 0b: feat fp32 [8192,512] -> bf16 ------------------
__global__ __launch_bounds__(256) void cvt_feat(const float* __restrict__ f,
                                                u16* __restrict__ fb) {
  const int i = (blockIdx.x * 256 + threadIdx.x) * 4;  // 4M elems / 4
  float4 v = *(const float4*)(f + i);
  u32 lo = (u32)bf16_rne(v.x) | ((u32)bf16_rne(v.y) << 16);
  u32 hi = (u32)bf16_rne(v.z) | ((u32)bf16_rne(v.w) << 16);
  *(uint2*)(fb + i) = make_uint2(lo, hi);
}

// ---------------- kernel 1: projections Q/16, K (row-major), VT ------------
// block = 32 m-rows; wave w owns nt-tiles {2w,2w+1}; ~12 waves/CU.
__global__ __launch_bounds__(256, 4) void proj_qkv(const u16* __restrict__ featb,
                                                   const u16* __restrict__ WT,
                                                   u16* __restrict__ Qs,
                                                   u16* __restrict__ Ks,
                                                   u16* __restrict__ VTs) {
  __shared__ u16 tl[4][32 * 40];  // per-wave transpose buffer, pitch 40 keeps 16B align
  const int mb = blockIdx.x, o = blockIdx.y;
  const int wave = threadIdx.x >> 6, lane = threadIdx.x & 63;
  const int mm = lane & 31, h = lane >> 5;
  const int m0 = mb * 32;
  const u16* wt = WT + o * (DD * IND);

  f32x16 acc[2];
#pragma unroll
  for (int t = 0; t < 2; ++t)
#pragma unroll
    for (int r = 0; r < 16; ++r) acc[t][r] = 0.f;

  for (int kc = 0; kc < 32; ++kc) {
    bf16x8 af = *(const bf16x8*)(featb + (size_t)(m0 + mm) * IND + kc * 16 + 8 * h);
#pragma unroll
    for (int t = 0; t < 2; ++t) {
      const int nt = wave * 2 + t;
      bf16x8 bf = *(const bf16x8*)(wt + (size_t)(nt * 32 + mm) * IND + kc * 16 + 8 * h);
      acc[t] = __builtin_amdgcn_mfma_f32_32x32x16_bf16(af, bf, acc[t], 0, 0, 0);
    }
  }

  if (o < 2) {
    const float sc = (o == 0) ? 0.0625f : 1.f;  // fold 1/sqrt(256) into Q
    u16* dst = (o == 0) ? Qs : Ks;
#pragma unroll
    for (int t = 0; t < 2; ++t) {
      const int nt = wave * 2 + t;
#pragma unroll
      for (int r = 0; r < 16; ++r) {
        const int mrow = (r & 3) + 8 * (r >> 2) + 4 * h;
        dst[(size_t)(m0 + mrow) * DD + nt * 32 + mm] = bf16_rne(acc[t][r] * sc);
      }
    }
  } else {
    // V -> VT via wave-private LDS transpose (no barriers needed)
    const int n2 = lane >> 1, mh = lane & 1;
#pragma unroll
    for (int t = 0; t < 2; ++t) {
      const int nt = wave * 2 + t;
#pragma unroll
      for (int r = 0; r < 16; r += 2) {
        const int mrow = (r & 3) + 8 * (r >> 2) + 4 * h;  // even; pair (r,r+1)->(m,m+1)
        u32 pk = (u32)bf16_rne(acc[t][r]) | ((u32)bf16_rne(acc[t][r + 1]) << 16);
        *(u32*)(&tl[wave][mm * 40 + mrow]) = pk;
      }
      // wave-internal LDS RAW/WAR: compiler orders + inserts lgkmcnt
      bf16x8 t0 = *(const bf16x8*)(&tl[wave][n2 * 40 + mh * 16]);
      bf16x8 t1 = *(const bf16x8*)(&tl[wave][n2 * 40 + mh * 16 + 8]);
      u16* gp = VTs + (size_t)(nt * 32 + n2) * NN + m0 + mh * 16;
      *(bf16x8*)(gp) = t0;
      *(bf16x8*)(gp + 8) = t1;
    }
  }
}

// ---------------- kernel 2: fused flash attention ---------------------------
// wave = 32 Q-rows; S^T = K.Q^T (32x32x16 MFMA); O' = V^T.P ; j-split spl ways
// cnt (counting_attn) is the only zero-reuse HBM stream (256 MB). Its per-iter
// shape (128 rows x 32KB stride, 128 B/row) page-thrashes DRAM -> ~1.1 TB/s.
// Fix: 4-iter register batch (cbat[4][4] float4, statically indexed) = 512 B
// per row per touch -> 4x fewer DRAM page activations. Waitcnt discipline:
//   batch start: vmcnt(16) = drain prev stage (oldest 8), keep 16 cf loads
//   sub-iters 1-3: vmcnt(0)  = exactly the one outstanding 8-op stage
//   stage for next chunk issued AFTER the barrier, in flight a full iter.
// T13 defer-max (THR=8) retained from round 3.
__global__ __launch_bounds__(256, 2) void flash_attn(const u16* __restrict__ Qs,
                                                     const u16* __restrict__ Ks,
                                                     const u16* __restrict__ VTs,
                                                     const float* __restrict__ cnt,
                                                     float* __restrict__ ml,
                                                     float* __restrict__ Op,
                                                     int jiters, int spl) {
  __shared__ u16 kl[2][8192];  // K chunk, 16B-block layout (kb*32 + j)
  __shared__ u16 vl[2][8192];  // VT chunk, 16B-block layout (jb*256 + n)
  const int bid = blockIdx.x;
  const int lg = __ffs(spl) - 1;
  const int sp = bid & (spl - 1);  // == XCD id (round-robin): K/V slice L2-local
  const int rb = bid >> lg;
  const int wave = threadIdx.x >> 6, lane = threadIdx.x & 63;
  const int mm = lane & 31, h = lane >> 5;
  const int m0 = rb * 128 + wave * 32;
  const int jbase = sp * jiters * 32;

  // persistent Q fragments: B-operand, lane holds Q[m0+mm][kc*16 + 8h .. +7]
  bf16x8 qf[16];
  {
    const u16* qrow = Qs + (size_t)(m0 + mm) * DD;
#pragma unroll
    for (int c = 0; c < 16; ++c) qf[c] = *(const bf16x8*)(qrow + c * 16 + 8 * h);
  }
  f32x16 acc[8];
#pragma unroll
  for (int nt = 0; nt < 8; ++nt)
#pragma unroll
    for (int r = 0; r < 16; ++r) acc[nt][r] = 0.f;
  float m_run = -1e30f, l_run = 0.f;

  // prologue: stage chunk 0 into buffer 0 (8 gl_lds per wave)
#pragma unroll
  for (int ii = 0; ii < 4; ++ii) {
    const int w = wave * 4 + ii;
    const int L = w * 64 + lane;
    gl_lds16(Ks + (size_t)(jbase + (L & 31)) * DD + (L >> 5) * 8, (char*)kl + w * 1024);
    gl_lds16(VTs + (size_t)(L & 255) * NN + jbase + (L >> 8) * 8, (char*)vl + w * 1024);
  }

  for (int jc = 0; jc < jiters; jc += 4) {
    // batch cf loads: 16 x dwordx4, 512 B per row, oldest vm ops of the batch
    float4 cbat[4][4];
    {
      const float* crow = cnt + (size_t)(m0 + mm) * NN + jbase + jc * 32 + 4 * h;
#pragma unroll
      for (int k = 0; k < 4; ++k)
#pragma unroll
        for (int g = 0; g < 4; ++g) cbat[k][g] = *(const float4*)(crow + k * 32 + 8 * g);
    }

#pragma unroll
    for (int k = 0; k < 4; ++k) {
      const int jb = jc + k;
      const int buf = jb & 1;
      const int j0 = jbase + jb * 32;

      // wait own previous stage; keep cf batch in flight at batch start
      if (k == 0)
        asm volatile("s_waitcnt vmcnt(16)" ::: "memory");
      else
        asm volatile("s_waitcnt vmcnt(0)" ::: "memory");
      __builtin_amdgcn_s_barrier();
      asm volatile("" ::: "memory");  // keep following gl_lds below the barrier

      // stage NEXT chunk into buf^1 (read last iter; safe after barrier)
      if (jb + 1 < jiters) {
        const int jn = j0 + 32;
#pragma unroll
        for (int ii = 0; ii < 4; ++ii) {
          const int w = wave * 4 + ii;
          const int L = w * 64 + lane;
          gl_lds16(Ks + (size_t)(jn + (L & 31)) * DD + (L >> 5) * 8,
                   (char*)kl + (buf ^ 1) * 16384 + w * 1024);
          gl_lds16(VTs + (size_t)(L & 255) * NN + jn + (L >> 8) * 8,
                   (char*)vl + (buf ^ 1) * 16384 + w * 1024);
        }
      }

      // S^T accumulate from current buffer, two chains for ILP
      const char* klb = (const char*)kl + buf * 16384;
      const char* vlb = (const char*)vl + buf * 16384;
      f32x16 sv0, sv1;
#pragma unroll
      for (int r = 0; r < 16; ++r) { sv0[r] = 0.f; sv1[r] = 0.f; }
      __builtin_amdgcn_s_setprio(1);
#pragma unroll
      for (int c = 0; c < 16; c += 2) {
        bf16x8 kf0 = *(const bf16x8*)(klb + (((2 * c + h) * 32 + mm) << 4));
        bf16x8 kf1 = *(const bf16x8*)(klb + (((2 * c + 2 + h) * 32 + mm) << 4));
        sv0 = __builtin_amdgcn_mfma_f32_32x32x16_bf16(kf0, qf[c], sv0, 0, 0, 0);
        sv1 = __builtin_amdgcn_mfma_f32_32x32x16_bf16(kf1, qf[c + 1], sv1, 0, 0, 0);
      }
      __builtin_amdgcn_s_setprio(0);
      f32x16 sv = sv0 + sv1;

      // cf for this sub-iter (static unrolled -> pure register aliasing)
      float cf[16];
#pragma unroll
      for (int g = 0; g < 4; ++g) {
        cf[4 * g + 0] = cbat[k][g].x;
        cf[4 * g + 1] = cbat[k][g].y;
        cf[4 * g + 2] = cbat[k][g].z;
        cf[4 * g + 3] = cbat[k][g].w;
      }

      // online softmax, defer-max: per-lane state indexed by mm (q-row)
      float ma = fmaxf(fmaxf(sv[0], sv[1]), sv[2]);
      float mb2 = fmaxf(fmaxf(sv[3], sv[4]), sv[5]);
      float mc = fmaxf(fmaxf(sv[6], sv[7]), sv[8]);
      float md = fmaxf(fmaxf(sv[9], sv[10]), sv[11]);
      float me = fmaxf(fmaxf(sv[12], sv[13]), sv[14]);
      float mx = fmaxf(fmaxf(fmaxf(ma, mb2), mc), fmaxf(fmaxf(md, me), sv[15]));
      mx = fmaxf(mx, __shfl_xor(mx, 32));

      const bool upd = __any(mx > m_run + 8.f);  // T13: tolerate growth <= 8
      if (upd) {
        const float m_new = fmaxf(m_run, mx);
        const float alpha = __expf(m_run - m_new);
        l_run *= alpha;
#pragma unroll
        for (int nt = 0; nt < 8; ++nt)
#pragma unroll
          for (int r = 0; r < 16; ++r) acc[nt][r] *= alpha;
        m_run = m_new;
      }
      const float msub = m_run - LN_K;

      float p[16];
#pragma unroll
      for (int r = 0; r < 16; ++r) p[r] = __expf(sv[r] - msub) * cf[r];
      // balanced sum tree (no fast-math reassociation at -O3)
      float s0 = (p[0] + p[1]) + (p[2] + p[3]);
      float s1 = (p[4] + p[5]) + (p[6] + p[7]);
      float s2 = (p[8] + p[9]) + (p[10] + p[11]);
      float s3 = (p[12] + p[13]) + (p[14] + p[15]);
      float bsum = (s0 + s1) + (s2 + s3);
      bsum += __shfl_xor(bsum, 32);
      l_run += bsum;

      // pack P pairs (bf16 trunc; bias cancelled by LN_K scale)
      u32 P2[8];
#pragma unroll
      for (int j = 0; j < 8; ++j) {
        const u32 ua = __float_as_uint(p[2 * j]);
        const u32 ub = __float_as_uint(p[2 * j + 1]);
        P2[j] = (ua >> 16) | (ub & 0xFFFF0000u);
      }
      // PV: O'[n][mm] += V^T[n][jj] * P[jj][mm]
#pragma unroll
      for (int kc2 = 0; kc2 < 2; ++kc2) {
        union { u32 u[4]; bf16x8 v; } pf;
#pragma unroll
        for (int tp = 0; tp < 4; ++tp) {
          const int src = mm + 32 * (tp >> 1);
          const u32 va = __shfl(P2[4 * kc2 + (tp & 1)], src);
          const u32 vb = __shfl(P2[4 * kc2 + 2 + (tp & 1)], src);
          pf.u[tp] = h ? vb : va;
        }
        __builtin_amdgcn_s_setprio(1);
#pragma unroll
        for (int nt = 0; nt < 8; ++nt) {
          bf16x8 vf = *(const bf16x8*)(vlb + ((((2 * kc2 + h) * 256) + nt * 32 + mm) << 4));
          acc[nt] = __builtin_amdgcn_mfma_f32_32x32x16_bf16(vf, pf.v, acc[nt], 0, 0, 0);
        }
        __builtin_amdgcn_s_setprio(0);
      }
      // no end-of-iter barrier: next sub-iter's vmcnt+s_barrier protects reuse
    }
  }

  // partials
  const int wb = rb * 4 + wave;
  if (lane < 32) {
    ml[((sp * 256 + wb) << 6) + lane] = m_run;
    ml[((sp * 256 + wb) << 6) + 32 + lane] = l_run;
  }
#pragma unroll
  for (int nt = 0; nt < 8; ++nt) {
#pragma unroll
    for (int rr = 0; rr < 4; ++rr) {
      // lane-major: wave stores 1KB contiguous per (nt,rr)
      float* op = Op + ((((size_t)(sp * 256 + wb) * 8 + nt) * 4 + rr) * 64 + lane) * 4;
      float4 v = make_float4(acc[nt][4 * rr], acc[nt][4 * rr + 1],
                             acc[nt][4 * rr + 2], acc[nt][4 * rr + 3]);
      *(float4*)op = v;
    }
  }
}

// ---------------- kernel 3: merge splits + elu + fp32 out ------------------
// Templated on SPL: runtime-indexed mv/lv/wsc arrays were rule-20 scratch.
template <int SPL>
__global__ __launch_bounds__(256) void merge_out(const float* __restrict__ ml,
                                                 const float* __restrict__ Op,
                                                 float* __restrict__ out) {
  const int wid = blockIdx.x * 4 + (threadIdx.x >> 6);
  const int lane = threadIdx.x & 63, mm = lane & 31, h = lane >> 5;
  const int wb = wid >> 3, nt = wid & 7;
  float mv[SPL], lv[SPL], wsc[SPL];
#pragma unroll
  for (int s = 0; s < SPL; ++s) {
    mv[s] = ml[((s * 256 + wb) << 6) + mm];
    lv[s] = ml[((s * 256 + wb) << 6) + 32 + mm];
  }
  float M = mv[0];
#pragma unroll
  for (int s = 1; s < SPL; ++s) M = fmaxf(M, mv[s]);
  float L = 0.f;
#pragma unroll
  for (int s = 0; s < SPL; ++s) {
    wsc[s] = __expf(mv[s] - M);
    L += wsc[s] * lv[s];
  }
  const float inv = 1.f / (L + 1e-9f);

  float o[16];
#pragma unroll
  for (int r = 0; r < 16; ++r) o[r] = 0.f;
#pragma unroll
  for (int s = 0; s < SPL; ++s) {
#pragma unroll
    for (int rr = 0; rr < 4; ++rr) {
      const float* op = Op + ((((size_t)(s * 256 + wb) * 8 + nt) * 4 + rr) * 64 + lane) * 4;
      float4 v = *(const float4*)op;
      o[4 * rr + 0] += wsc[s] * v.x;
      o[4 * rr + 1] += wsc[s] * v.y;
      o[4 * rr + 2] += wsc[s] * v.z;
      o[4 * rr + 3] += wsc[s] * v.w;
    }
  }
  // out[row][col], col = (r&3) + 8*(r>>2) + 4h: contiguous float4 per g=r>>2
  const int row = wb * 32 + mm;
#pragma unroll
  for (int g = 0; g < 4; ++g) {
    float4 v;
    float* pv = &v.x;
#pragma unroll
    for (int i = 0; i < 4; ++i) {
      float t = o[4 * g + i] * inv;
      pv[i] = t > 0.f ? t : expm1f(t);  // elu, alpha=1
    }
    *(float4*)(out + (size_t)row * DD + nt * 32 + 8 * g + 4 * h) = v;
  }
}

extern "C" void kernel_launch(void* const* d_in, const int* in_sizes, int n_in,
                              void* d_out, int out_size, void* d_ws, size_t ws_size,
                              hipStream_t stream) {
  const float* feat = (const float*)d_in[0];
  const float* cnta = (const float*)d_in[1];
  const float* Wq = (const float*)d_in[2];
  const float* Wk = (const float*)d_in[3];
  const float* Wv = (const float*)d_in[4];
  char* ws = (char*)d_ws;
  u16* WT = (u16*)(ws);                      // 768 KB
  u16* featb = (u16*)(ws + (1ull << 20));    // 8 MB
  u16* Qs = (u16*)(ws + (9ull << 20));       // 4 MB
  u16* Ks = (u16*)(ws + (13ull << 20));      // 4 MB
  u16* VTs = (u16*)(ws + (17ull << 20));     // 4 MB
  float* ml = (float*)(ws + (21ull << 20));  // 1 MB (spl<=8)
  float* Op = (float*)(ws + (22ull << 20));  // spl*8 MB
  float* out = (float*)d_out;

  // spl=8 needs 22MB + 64MB = 86MB of ws; fall back to proven 54MB layout.
  const size_t need8 = (22ull << 20) + (64ull << 20);
  const int spl = (ws_size >= need8) ? 8 : 4;
  const int jiters = NN / (spl * 32);

  hipLaunchKernelGGL(wt_transpose, dim3(64, 3), dim3(256), 0, stream, Wq, Wk, Wv, WT);
  hipLaunchKernelGGL(cvt_feat, dim3(4096), dim3(256), 0, stream, feat, featb);
  hipLaunchKernelGGL(proj_qkv, dim3(256, 3), dim3(256), 0, stream, featb, WT, Qs, Ks, VTs);
  // 1-D grid: bid % spl == XCD (round-robin) -> each XCD owns one j-slice
  hipLaunchKernelGGL(flash_attn, dim3(64 * spl), dim3(256), 0, stream, Qs, Ks, VTs, cnta, ml,
                     Op, jiters, spl);
  if (spl == 8) {
    hipLaunchKernelGGL((merge_out<8>), dim3(512), dim3(256), 0, stream, ml, Op, out);
  } else {
    hipLaunchKernelGGL((merge_out<4>), dim3(512), dim3(256), 0, stream, ml, Op, out);
  }
}

// Round 6
// 538.515 us; speedup vs baseline: 1.3619x; 1.3619x over previous
//
#include <hip/hip_runtime.h>

typedef unsigned short u16;
typedef unsigned int u32;
typedef __attribute__((ext_vector_type(8))) __bf16 bf16x8;
typedef __attribute__((ext_vector_type(16))) float f32x16;

#define NN 8192
#define IND 512
#define DD 256
// ln(1 + 2^-9): folded into exp so that bf16-truncation of P is unbiased
#define LN_K 0.00195122595f

__device__ __forceinline__ void gl_lds16(const void* g, void* l) {
  __builtin_amdgcn_global_load_lds((const __attribute__((address_space(1))) void*)g,
                                   (__attribute__((address_space(3))) void*)l, 16, 0, 0);
}
__device__ __forceinline__ u16 bf16_rne(float x) {
  u32 u = __float_as_uint(x);
  u += 0x7FFF + ((u >> 16) & 1);
  return (u16)(u >> 16);
}

// ---------------- kernel 0a: W fp32 [512,256] -> WT bf16 [256,512], x3 -----
// Coalesced reads (thread = n, k in a short loop), 16B packed store per thread.
__global__ __launch_bounds__(256) void wt_transpose(const float* __restrict__ Wq,
                                                    const float* __restrict__ Wk,
                                                    const float* __restrict__ Wv,
                                                    u16* __restrict__ WT) {
  const int o = blockIdx.y;
  const int k0 = blockIdx.x * 8;  // 64 blocks cover k<512
  const int n = threadIdx.x;
  const float* W = (o == 0) ? Wq : ((o == 1) ? Wk : Wv);
  u32 pk[4];
#pragma unroll
  for (int g = 0; g < 4; ++g) {
    const float a = W[(size_t)(k0 + 2 * g) * DD + n];      // coalesced across n
    const float b = W[(size_t)(k0 + 2 * g + 1) * DD + n];  // coalesced across n
    pk[g] = (u32)bf16_rne(a) | ((u32)bf16_rne(b) << 16);
  }
  *(uint4*)(WT + (size_t)o * (DD * IND) + (size_t)n * IND + k0) =
      make_uint4(pk[0], pk[1], pk[2], pk[3]);
}

// ---------------- kernel 0b: feat fp32 [8192,512] -> bf16 ------------------
__global__ __launch_bounds__(256) void cvt_feat(const float* __restrict__ f,
                                                u16* __restrict__ fb) {
  const int i = (blockIdx.x * 256 + threadIdx.x) * 4;  // 4M elems / 4
  float4 v = *(const float4*)(f + i);
  u32 lo = (u32)bf16_rne(v.x) | ((u32)bf16_rne(v.y) << 16);
  u32 hi = (u32)bf16_rne(v.z) | ((u32)bf16_rne(v.w) << 16);
  *(uint2*)(fb + i) = make_uint2(lo, hi);
}

// ---------------- kernel 1: projections Q/16, K (row-major), VT ------------
// block = 32 m-rows; wave w owns nt-tiles {2w,2w+1}; ~12 waves/CU.
__global__ __launch_bounds__(256, 4) void proj_qkv(const u16* __restrict__ featb,
                                                   const u16* __restrict__ WT,
                                                   u16* __restrict__ Qs,
                                                   u16* __restrict__ Ks,
                                                   u16* __restrict__ VTs) {
  __shared__ u16 tl[4][32 * 40];  // per-wave transpose buffer, pitch 40 keeps 16B align
  const int mb = blockIdx.x, o = blockIdx.y;
  const int wave = threadIdx.x >> 6, lane = threadIdx.x & 63;
  const int mm = lane & 31, h = lane >> 5;
  const int m0 = mb * 32;
  const u16* wt = WT + o * (DD * IND);

  f32x16 acc[2];
#pragma unroll
  for (int t = 0; t < 2; ++t)
#pragma unroll
    for (int r = 0; r < 16; ++r) acc[t][r] = 0.f;

  for (int kc = 0; kc < 32; ++kc) {
    bf16x8 af = *(const bf16x8*)(featb + (size_t)(m0 + mm) * IND + kc * 16 + 8 * h);
#pragma unroll
    for (int t = 0; t < 2; ++t) {
      const int nt = wave * 2 + t;
      bf16x8 bf = *(const bf16x8*)(wt + (size_t)(nt * 32 + mm) * IND + kc * 16 + 8 * h);
      acc[t] = __builtin_amdgcn_mfma_f32_32x32x16_bf16(af, bf, acc[t], 0, 0, 0);
    }
  }

  if (o < 2) {
    const float sc = (o == 0) ? 0.0625f : 1.f;  // fold 1/sqrt(256) into Q
    u16* dst = (o == 0) ? Qs : Ks;
#pragma unroll
    for (int t = 0; t < 2; ++t) {
      const int nt = wave * 2 + t;
#pragma unroll
      for (int r = 0; r < 16; ++r) {
        const int mrow = (r & 3) + 8 * (r >> 2) + 4 * h;
        dst[(size_t)(m0 + mrow) * DD + nt * 32 + mm] = bf16_rne(acc[t][r] * sc);
      }
    }
  } else {
    // V -> VT via wave-private LDS transpose (no barriers needed)
    const int n2 = lane >> 1, mh = lane & 1;
#pragma unroll
    for (int t = 0; t < 2; ++t) {
      const int nt = wave * 2 + t;
#pragma unroll
      for (int r = 0; r < 16; r += 2) {
        const int mrow = (r & 3) + 8 * (r >> 2) + 4 * h;  // even; pair (r,r+1)->(m,m+1)
        u32 pk = (u32)bf16_rne(acc[t][r]) | ((u32)bf16_rne(acc[t][r + 1]) << 16);
        *(u32*)(&tl[wave][mm * 40 + mrow]) = pk;
      }
      // wave-internal LDS RAW/WAR: compiler orders + inserts lgkmcnt
      bf16x8 t0 = *(const bf16x8*)(&tl[wave][n2 * 40 + mh * 16]);
      bf16x8 t1 = *(const bf16x8*)(&tl[wave][n2 * 40 + mh * 16 + 8]);
      u16* gp = VTs + (size_t)(nt * 32 + n2) * NN + m0 + mh * 16;
      *(bf16x8*)(gp) = t0;
      *(bf16x8*)(gp + 8) = t1;
    }
  }
}

// ---------------- kernel 2: fused flash attention ---------------------------
// wave = 32 Q-rows; S^T = K.Q^T (32x32x16 MFMA); O' = V^T.P ; j-split spl ways
// Pipeline (proven in round 3, 225us):
//   - cf loads issued FIRST each iter; vmcnt(4)+raw s_barrier waits only the
//     previous 8-op K/V stage; stage for next chunk issued after the barrier.
//   - T13 defer-max (THR=8).
// Round 5 (re-run; round-5 bench was an infra failure, kernel never executed):
// per-block j-ring STAGGER. All 512 blocks previously marched the j-loop in
// lockstep, so the whole device read the same 128B column-slice of cnt
// simultaneously; with 32KB row stride likely aliasing one channel stripe,
// each sp hammered ~1 DRAM channel -> ~1.1TB/s ceiling invariant to pipeline
// depth. jb = (t + 7*rb) % jiters de-phases blocks across 32 distinct column
// regions. Online softmax is j-order-invariant, so this is free.
// HARD CONSTRAINT (round-4 lesson): 128 VGPR + 128 AGPR = zero headroom;
// never add live register state to this kernel (spills -> 2x regression).
__global__ __launch_bounds__(256, 2) void flash_attn(const u16* __restrict__ Qs,
                                                     const u16* __restrict__ Ks,
                                                     const u16* __restrict__ VTs,
                                                     const float* __restrict__ cnt,
                                                     float* __restrict__ ml,
                                                     float* __restrict__ Op,
                                                     int jiters, int spl) {
  __shared__ u16 kl[2][8192];  // K chunk, 16B-block layout (kb*32 + j)
  __shared__ u16 vl[2][8192];  // VT chunk, 16B-block layout (jb*256 + n)
  const int bid = blockIdx.x;
  const int lg = __ffs(spl) - 1;
  const int sp = bid & (spl - 1);  // == XCD id (round-robin): K/V slice L2-local
  const int rb = bid >> lg;
  const int wave = threadIdx.x >> 6, lane = threadIdx.x & 63;
  const int mm = lane & 31, h = lane >> 5;
  const int m0 = rb * 128 + wave * 32;
  const int jbase = sp * jiters * 32;
  const int off = (rb * 7) & (jiters - 1);  // j-ring rotation (jiters is pow2)

  // persistent Q fragments: B-operand, lane holds Q[m0+mm][kc*16 + 8h .. +7]
  bf16x8 qf[16];
  {
    const u16* qrow = Qs + (size_t)(m0 + mm) * DD;
#pragma unroll
    for (int c = 0; c < 16; ++c) qf[c] = *(const bf16x8*)(qrow + c * 16 + 8 * h);
  }
  f32x16 acc[8];
#pragma unroll
  for (int nt = 0; nt < 8; ++nt)
#pragma unroll
    for (int r = 0; r < 16; ++r) acc[nt][r] = 0.f;
  float m_run = -1e30f, l_run = 0.f;

  // prologue: stage chunk phys(0) into buffer 0 (8 gl_lds per wave)
  {
    const int j00 = jbase + off * 32;
#pragma unroll
    for (int ii = 0; ii < 4; ++ii) {
      const int w = wave * 4 + ii;
      const int L = w * 64 + lane;
      gl_lds16(Ks + (size_t)(j00 + (L & 31)) * DD + (L >> 5) * 8, (char*)kl + w * 1024);
      gl_lds16(VTs + (size_t)(L & 255) * NN + j00 + (L >> 8) * 8, (char*)vl + w * 1024);
    }
  }

  for (int t = 0; t < jiters; ++t) {
    const int jb = (t + off) & (jiters - 1);  // staggered physical chunk index
    const int buf = t & 1;
    const int j0 = jbase + jb * 32;

    // 1. counting_attn for this lane's 16 jj slots: jj(r) = (r&3)+8*(r>>2)+4h
    float cf[16];
    {
      const float* crow = cnt + (size_t)(m0 + mm) * NN + j0 + 4 * h;
#pragma unroll
      for (int g = 0; g < 4; ++g) {
        float4 t4 = *(const float4*)(crow + 8 * g);
        cf[4 * g + 0] = t4.x;
        cf[4 * g + 1] = t4.y;
        cf[4 * g + 2] = t4.z;
        cf[4 * g + 3] = t4.w;
      }
    }

    // 2. wait own previous stage (cf's 4 loads stay in flight), then sync
    asm volatile("s_waitcnt vmcnt(4)" ::: "memory");
    __builtin_amdgcn_s_barrier();
    asm volatile("" ::: "memory");  // keep following gl_lds below the barrier

    // 3. stage NEXT chunk into buf^1 (read last iter; safe after barrier)
    if (t + 1 < jiters) {
      const int jn = jbase + ((t + 1 + off) & (jiters - 1)) * 32;
#pragma unroll
      for (int ii = 0; ii < 4; ++ii) {
        const int w = wave * 4 + ii;
        const int L = w * 64 + lane;
        gl_lds16(Ks + (size_t)(jn + (L & 31)) * DD + (L >> 5) * 8,
                 (char*)kl + (buf ^ 1) * 16384 + w * 1024);
        gl_lds16(VTs + (size_t)(L & 255) * NN + jn + (L >> 8) * 8,
                 (char*)vl + (buf ^ 1) * 16384 + w * 1024);
      }
    }

    // 4. S^T accumulate from current buffer, two chains for ILP
    const char* klb = (const char*)kl + buf * 16384;
    const char* vlb = (const char*)vl + buf * 16384;
    f32x16 sv0, sv1;
#pragma unroll
    for (int r = 0; r < 16; ++r) { sv0[r] = 0.f; sv1[r] = 0.f; }
    __builtin_amdgcn_s_setprio(1);
#pragma unroll
    for (int c = 0; c < 16; c += 2) {
      bf16x8 kf0 = *(const bf16x8*)(klb + (((2 * c + h) * 32 + mm) << 4));
      bf16x8 kf1 = *(const bf16x8*)(klb + (((2 * c + 2 + h) * 32 + mm) << 4));
      sv0 = __builtin_amdgcn_mfma_f32_32x32x16_bf16(kf0, qf[c], sv0, 0, 0, 0);
      sv1 = __builtin_amdgcn_mfma_f32_32x32x16_bf16(kf1, qf[c + 1], sv1, 0, 0, 0);
    }
    __builtin_amdgcn_s_setprio(0);
    f32x16 sv = sv0 + sv1;

    // 5. online softmax, defer-max: per-lane state indexed by mm (q-row)
    float ma = fmaxf(fmaxf(sv[0], sv[1]), sv[2]);
    float mb2 = fmaxf(fmaxf(sv[3], sv[4]), sv[5]);
    float mc = fmaxf(fmaxf(sv[6], sv[7]), sv[8]);
    float md = fmaxf(fmaxf(sv[9], sv[10]), sv[11]);
    float me = fmaxf(fmaxf(sv[12], sv[13]), sv[14]);
    float mx = fmaxf(fmaxf(fmaxf(ma, mb2), mc), fmaxf(fmaxf(md, me), sv[15]));
    mx = fmaxf(mx, __shfl_xor(mx, 32));

    const bool upd = __any(mx > m_run + 8.f);  // T13: tolerate growth <= 8
    if (upd) {
      const float m_new = fmaxf(m_run, mx);
      const float alpha = __expf(m_run - m_new);
      l_run *= alpha;
#pragma unroll
      for (int nt = 0; nt < 8; ++nt)
#pragma unroll
        for (int r = 0; r < 16; ++r) acc[nt][r] *= alpha;
      m_run = m_new;
    }
    const float msub = m_run - LN_K;

    float p[16];
#pragma unroll
    for (int r = 0; r < 16; ++r) p[r] = __expf(sv[r] - msub) * cf[r];
    // balanced sum tree (no fast-math reassociation at -O3)
    float s0 = (p[0] + p[1]) + (p[2] + p[3]);
    float s1 = (p[4] + p[5]) + (p[6] + p[7]);
    float s2 = (p[8] + p[9]) + (p[10] + p[11]);
    float s3 = (p[12] + p[13]) + (p[14] + p[15]);
    float bsum = (s0 + s1) + (s2 + s3);
    bsum += __shfl_xor(bsum, 32);
    l_run += bsum;

    // 6. pack P pairs (bf16 trunc; bias cancelled by LN_K scale)
    u32 P2[8];
#pragma unroll
    for (int j = 0; j < 8; ++j) {
      const u32 ua = __float_as_uint(p[2 * j]);
      const u32 ub = __float_as_uint(p[2 * j + 1]);
      P2[j] = (ua >> 16) | (ub & 0xFFFF0000u);
    }
    // 7. PV: O'[n][mm] += V^T[n][jj] * P[jj][mm]
#pragma unroll
    for (int kc2 = 0; kc2 < 2; ++kc2) {
      union { u32 u[4]; bf16x8 v; } pf;
#pragma unroll
      for (int tp = 0; tp < 4; ++tp) {
        const int src = mm + 32 * (tp >> 1);
        const u32 va = __shfl(P2[4 * kc2 + (tp & 1)], src);
        const u32 vb = __shfl(P2[4 * kc2 + 2 + (tp & 1)], src);
        pf.u[tp] = h ? vb : va;
      }
      __builtin_amdgcn_s_setprio(1);
#pragma unroll
      for (int nt = 0; nt < 8; ++nt) {
        bf16x8 vf = *(const bf16x8*)(vlb + ((((2 * kc2 + h) * 256) + nt * 32 + mm) << 4));
        acc[nt] = __builtin_amdgcn_mfma_f32_32x32x16_bf16(vf, pf.v, acc[nt], 0, 0, 0);
      }
      __builtin_amdgcn_s_setprio(0);
    }
    // no end-of-iter barrier: next iter's vmcnt(4)+s_barrier protects reuse
  }

  // partials
  const int wb = rb * 4 + wave;
  if (lane < 32) {
    ml[((sp * 256 + wb) << 6) + lane] = m_run;
    ml[((sp * 256 + wb) << 6) + 32 + lane] = l_run;
  }
#pragma unroll
  for (int nt = 0; nt < 8; ++nt) {
#pragma unroll
    for (int rr = 0; rr < 4; ++rr) {
      // lane-major: wave stores 1KB contiguous per (nt,rr)
      float* op = Op + ((((size_t)(sp * 256 + wb) * 8 + nt) * 4 + rr) * 64 + lane) * 4;
      float4 v = make_float4(acc[nt][4 * rr], acc[nt][4 * rr + 1],
                             acc[nt][4 * rr + 2], acc[nt][4 * rr + 3]);
      *(float4*)op = v;
    }
  }
}

// ---------------- kernel 3: merge splits + elu + fp32 out ------------------
// Templated on SPL: runtime-indexed mv/lv/wsc arrays were rule-20 scratch.
template <int SPL>
__global__ __launch_bounds__(256) void merge_out(const float* __restrict__ ml,
                                                 const float* __restrict__ Op,
                                                 float* __restrict__ out) {
  const int wid = blockIdx.x * 4 + (threadIdx.x >> 6);
  const int lane = threadIdx.x & 63, mm = lane & 31, h = lane >> 5;
  const int wb = wid >> 3, nt = wid & 7;
  float mv[SPL], lv[SPL], wsc[SPL];
#pragma unroll
  for (int s = 0; s < SPL; ++s) {
    mv[s] = ml[((s * 256 + wb) << 6) + mm];
    lv[s] = ml[((s * 256 + wb) << 6) + 32 + mm];
  }
  float M = mv[0];
#pragma unroll
  for (int s = 1; s < SPL; ++s) M = fmaxf(M, mv[s]);
  float L = 0.f;
#pragma unroll
  for (int s = 0; s < SPL; ++s) {
    wsc[s] = __expf(mv[s] - M);
    L += wsc[s] * lv[s];
  }
  const float inv = 1.f / (L + 1e-9f);

  float o[16];
#pragma unroll
  for (int r = 0; r < 16; ++r) o[r] = 0.f;
#pragma unroll
  for (int s = 0; s < SPL; ++s) {
#pragma unroll
    for (int rr = 0; rr < 4; ++rr) {
      const float* op = Op + ((((size_t)(s * 256 + wb) * 8 + nt) * 4 + rr) * 64 + lane) * 4;
      float4 v = *(const float4*)op;
      o[4 * rr + 0] += wsc[s] * v.x;
      o[4 * rr + 1] += wsc[s] * v.y;
      o[4 * rr + 2] += wsc[s] * v.z;
      o[4 * rr + 3] += wsc[s] * v.w;
    }
  }
  // out[row][col], col = (r&3) + 8*(r>>2) + 4h: contiguous float4 per g=r>>2
  const int row = wb * 32 + mm;
#pragma unroll
  for (int g = 0; g < 4; ++g) {
    float4 v;
    float* pv = &v.x;
#pragma unroll
    for (int i = 0; i < 4; ++i) {
      float t = o[4 * g + i] * inv;
      pv[i] = t > 0.f ? t : expm1f(t);  // elu, alpha=1
    }
    *(float4*)(out + (size_t)row * DD + nt * 32 + 8 * g + 4 * h) = v;
  }
}

extern "C" void kernel_launch(void* const* d_in, const int* in_sizes, int n_in,
                              void* d_out, int out_size, void* d_ws, size_t ws_size,
                              hipStream_t stream) {
  const float* feat = (const float*)d_in[0];
  const float* cnta = (const float*)d_in[1];
  const float* Wq = (const float*)d_in[2];
  const float* Wk = (const float*)d_in[3];
  const float* Wv = (const float*)d_in[4];
  char* ws = (char*)d_ws;
  u16* WT = (u16*)(ws);                      // 768 KB
  u16* featb = (u16*)(ws + (1ull << 20));    // 8 MB
  u16* Qs = (u16*)(ws + (9ull << 20));       // 4 MB
  u16* Ks = (u16*)(ws + (13ull << 20));      // 4 MB
  u16* VTs = (u16*)(ws + (17ull << 20));     // 4 MB
  float* ml = (float*)(ws + (21ull << 20));  // 1 MB (spl<=8)
  float* Op = (float*)(ws + (22ull << 20));  // spl*8 MB
  float* out = (float*)d_out;

  // spl=8 needs 22MB + 64MB = 86MB of ws; fall back to proven 54MB layout.
  const size_t need8 = (22ull << 20) + (64ull << 20);
  const int spl = (ws_size >= need8) ? 8 : 4;
  const int jiters = NN / (spl * 32);

  hipLaunchKernelGGL(wt_transpose, dim3(64, 3), dim3(256), 0, stream, Wq, Wk, Wv, WT);
  hipLaunchKernelGGL(cvt_feat, dim3(4096), dim3(256), 0, stream, feat, featb);
  hipLaunchKernelGGL(proj_qkv, dim3(256, 3), dim3(256), 0, stream, featb, WT, Qs, Ks, VTs);
  // 1-D grid: bid % spl == XCD (round-robin) -> each XCD owns one j-slice
  hipLaunchKernelGGL(flash_attn, dim3(64 * spl), dim3(256), 0, stream, Qs, Ks, VTs, cnta, ml,
                     Op, jiters, spl);
  if (spl == 8) {
    hipLaunchKernelGGL((merge_out<8>), dim3(512), dim3(256), 0, stream, ml, Op, out);
  } else {
    hipLaunchKernelGGL((merge_out<4>), dim3(512), dim3(256), 0, stream, ml, Op, out);
  }
}

// Round 7
// 475.712 us; speedup vs baseline: 1.5417x; 1.1320x over previous
//
#include <hip/hip_runtime.h>

typedef unsigned short u16;
typedef unsigned int u32;
typedef __attribute__((ext_vector_type(8))) __bf16 bf16x8;
typedef __attribute__((ext_vector_type(16))) float f32x16;

#define NN 8192
#define IND 512
#define DD 256
// ln(1 + 2^-9): folded into exp so that bf16-truncation of P is unbiased
#define LN_K 0.00195122595f

__device__ __forceinline__ void gl_lds16(const void* g, void* l) {
  __builtin_amdgcn_global_load_lds((const __attribute__((address_space(1))) void*)g,
                                   (__attribute__((address_space(3))) void*)l, 16, 0, 0);
}
__device__ __forceinline__ u16 bf16_rne(float x) {
  u32 u = __float_as_uint(x);
  u += 0x7FFF + ((u >> 16) & 1);
  return (u16)(u >> 16);
}

// ---------------- kernel 0a: W fp32 [512,256] -> WT bf16 [256,512], x3 -----
__global__ __launch_bounds__(256) void wt_transpose(const float* __restrict__ Wq,
                                                    const float* __restrict__ Wk,
                                                    const float* __restrict__ Wv,
                                                    u16* __restrict__ WT) {
  const int o = blockIdx.y;
  const int k0 = blockIdx.x * 8;  // 64 blocks cover k<512
  const int n = threadIdx.x;
  const float* W = (o == 0) ? Wq : ((o == 1) ? Wk : Wv);
  u32 pk[4];
#pragma unroll
  for (int g = 0; g < 4; ++g) {
    const float a = W[(size_t)(k0 + 2 * g) * DD + n];      // coalesced across n
    const float b = W[(size_t)(k0 + 2 * g + 1) * DD + n];  // coalesced across n
    pk[g] = (u32)bf16_rne(a) | ((u32)bf16_rne(b) << 16);
  }
  *(uint4*)(WT + (size_t)o * (DD * IND) + (size_t)n * IND + k0) =
      make_uint4(pk[0], pk[1], pk[2], pk[3]);
}

// ---------------- kernel 0b: feat fp32 [8192,512] -> bf16 ------------------
__global__ __launch_bounds__(256) void cvt_feat(const float* __restrict__ f,
                                                u16* __restrict__ fb) {
  const int i = (blockIdx.x * 256 + threadIdx.x) * 4;  // 4M elems / 4
  float4 v = *(const float4*)(f + i);
  u32 lo = (u32)bf16_rne(v.x) | ((u32)bf16_rne(v.y) << 16);
  u32 hi = (u32)bf16_rne(v.z) | ((u32)bf16_rne(v.w) << 16);
  *(uint2*)(fb + i) = make_uint2(lo, hi);
}

// ---------------- kernel 1: projections Q/16, K (row-major), VT ------------
// block = 32 m-rows; wave w owns nt-tiles {2w,2w+1}; ~12 waves/CU.
__global__ __launch_bounds__(256, 4) void proj_qkv(const u16* __restrict__ featb,
                                                   const u16* __restrict__ WT,
                                                   u16* __restrict__ Qs,
                                                   u16* __restrict__ Ks,
                                                   u16* __restrict__ VTs) {
  __shared__ u16 tl[4][32 * 40];  // per-wave transpose buffer, pitch 40 keeps 16B align
  const int mb = blockIdx.x, o = blockIdx.y;
  const int wave = threadIdx.x >> 6, lane = threadIdx.x & 63;
  const int mm = lane & 31, h = lane >> 5;
  const int m0 = mb * 32;
  const u16* wt = WT + o * (DD * IND);

  f32x16 acc[2];
#pragma unroll
  for (int t = 0; t < 2; ++t)
#pragma unroll
    for (int r = 0; r < 16; ++r) acc[t][r] = 0.f;

  for (int kc = 0; kc < 32; ++kc) {
    bf16x8 af = *(const bf16x8*)(featb + (size_t)(m0 + mm) * IND + kc * 16 + 8 * h);
#pragma unroll
    for (int t = 0; t < 2; ++t) {
      const int nt = wave * 2 + t;
      bf16x8 bf = *(const bf16x8*)(wt + (size_t)(nt * 32 + mm) * IND + kc * 16 + 8 * h);
      acc[t] = __builtin_amdgcn_mfma_f32_32x32x16_bf16(af, bf, acc[t], 0, 0, 0);
    }
  }

  if (o < 2) {
    const float sc = (o == 0) ? 0.0625f : 1.f;  // fold 1/sqrt(256) into Q
    u16* dst = (o == 0) ? Qs : Ks;
#pragma unroll
    for (int t = 0; t < 2; ++t) {
      const int nt = wave * 2 + t;
#pragma unroll
      for (int r = 0; r < 16; ++r) {
        const int mrow = (r & 3) + 8 * (r >> 2) + 4 * h;
        dst[(size_t)(m0 + mrow) * DD + nt * 32 + mm] = bf16_rne(acc[t][r] * sc);
      }
    }
  } else {
    // V -> VT via wave-private LDS transpose (no barriers needed)
    const int n2 = lane >> 1, mh = lane & 1;
#pragma unroll
    for (int t = 0; t < 2; ++t) {
      const int nt = wave * 2 + t;
#pragma unroll
      for (int r = 0; r < 16; r += 2) {
        const int mrow = (r & 3) + 8 * (r >> 2) + 4 * h;  // even; pair (r,r+1)->(m,m+1)
        u32 pk = (u32)bf16_rne(acc[t][r]) | ((u32)bf16_rne(acc[t][r + 1]) << 16);
        *(u32*)(&tl[wave][mm * 40 + mrow]) = pk;
      }
      // wave-internal LDS RAW/WAR: compiler orders + inserts lgkmcnt
      bf16x8 t0 = *(const bf16x8*)(&tl[wave][n2 * 40 + mh * 16]);
      bf16x8 t1 = *(const bf16x8*)(&tl[wave][n2 * 40 + mh * 16 + 8]);
      u16* gp = VTs + (size_t)(nt * 32 + n2) * NN + m0 + mh * 16;
      *(bf16x8*)(gp) = t0;
      *(bf16x8*)(gp + 8) = t1;
    }
  }
}

// ---------------- kernel 2: fused flash attention ---------------------------
// ROUND 7 RESTRUCTURE. Diagnosis: per-iter 16.7K cy vs ~1K issue; the ONLY
// same-iter-issued+consumed memory dep is cf (counting_attn) -> softmax eats
// ~15K cy of congested-HBM latency each iter. Round-4's register prefetch was
// the right test but spilled: launch_bounds(_,2) caps the unified file at 256
// regs/wave and the kernel sits at exactly 128 VGPR + 128 AGPR.
// Fix with ZERO register cost: stage cf through LDS via global_load_lds with a
// full-iteration prefetch window, like K/V.
//   - block = 512 threads (8 waves, 256 rows), ONE block/CU.
//     LDS (dynamic) = K dbuf 32K + V dbuf 32K + cf dbuf 64K = 128KB.
//     Wave-level occupancy unchanged (8 waves/CU = 2/SIMD, as before).
//   - cf staging is wave-private (each wave stages+reads only its 32 rows):
//     no new barriers. Lane stages its own (mm,h) fragment -> LDS layout is
//     read-fragment-ordered; ds_read_b128 consecutive-mm = conflict-free.
//   - per-wave stage group = 4 K/V + 4 cf gl_lds. Counted waits:
//     top-of-iter vmcnt(4) (K/V landed, cf flies) + s_barrier;
//     after QK vmcnt(8) (retires exactly cf(t)); vmcnt(0) only at tail.
//   - T13 defer-max (THR=8), j-ring stagger, setprio retained.
__global__ __launch_bounds__(512, 2) void flash_attn(const u16* __restrict__ Qs,
                                                     const u16* __restrict__ Ks,
                                                     const u16* __restrict__ VTs,
                                                     const float* __restrict__ cnt,
                                                     float* __restrict__ ml,
                                                     float* __restrict__ Op,
                                                     int jiters, int spl) {
  extern __shared__ char smem[];
  char* kl = smem;           // 2 x 16KB : K chunk, 16B-block layout (kb*32 + j)
  char* vl = smem + 32768;   // 2 x 16KB : VT chunk, 16B-block layout (jb*256 + n)
  char* cfl = smem + 65536;  // 2 x 32KB : cf chunk, read-fragment layout
  const int bid = blockIdx.x;
  const int lg = __ffs(spl) - 1;
  const int sp = bid & (spl - 1);  // == XCD id (round-robin): K/V slice L2-local
  const int rb = bid >> lg;        // 0..31
  const int wave = threadIdx.x >> 6, lane = threadIdx.x & 63;
  const int mm = lane & 31, h = lane >> 5;
  const int m0 = rb * 256 + wave * 32;
  const int jbase = sp * jiters * 32;
  const int off = (rb * 7) & (jiters - 1);  // j-ring rotation (jiters is pow2)
  const float* crow = cnt + (size_t)(m0 + mm) * NN + 4 * h;  // lane's stage src base

  // persistent Q fragments: B-operand, lane holds Q[m0+mm][kc*16 + 8h .. +7]
  bf16x8 qf[16];
  {
    const u16* qrow = Qs + (size_t)(m0 + mm) * DD;
#pragma unroll
    for (int c = 0; c < 16; ++c) qf[c] = *(const bf16x8*)(qrow + c * 16 + 8 * h);
  }
  f32x16 acc[8];
#pragma unroll
  for (int nt = 0; nt < 8; ++nt)
#pragma unroll
    for (int r = 0; r < 16; ++r) acc[nt][r] = 0.f;
  float m_run = -1e30f, l_run = 0.f;

  // prologue: stage chunk phys(off): K/V (4 ops) then cf (4 ops) per wave
  {
    const int j00 = jbase + off * 32;
#pragma unroll
    for (int ii = 0; ii < 2; ++ii) {
      const int w = wave * 2 + ii;
      const int L = w * 64 + lane;
      gl_lds16(Ks + (size_t)(j00 + (L & 31)) * DD + (L >> 5) * 8, kl + w * 1024);
      gl_lds16(VTs + (size_t)(L & 255) * NN + j00 + (L >> 8) * 8, vl + w * 1024);
    }
#pragma unroll
    for (int ii = 0; ii < 4; ++ii)
      gl_lds16(crow + j00 + 8 * ii, cfl + wave * 4096 + ii * 1024);
  }

  for (int t = 0; t < jiters; ++t) {
    const int jb = (t + off) & (jiters - 1);  // staggered physical chunk index
    const int buf = t & 1;
    const int j0 = jbase + jb * 32;
    (void)j0;

    // 1. wait own previous K/V stage (own cf(t) 4 ops stay in flight), sync
    asm volatile("s_waitcnt vmcnt(4)" ::: "memory");
    __builtin_amdgcn_s_barrier();
    asm volatile("" ::: "memory");  // keep following gl_lds below the barrier

    // 2. stage NEXT chunk into buf^1: K/V then cf (order matters for vmcnt)
    if (t + 1 < jiters) {
      const int jn = jbase + ((t + 1 + off) & (jiters - 1)) * 32;
#pragma unroll
      for (int ii = 0; ii < 2; ++ii) {
        const int w = wave * 2 + ii;
        const int L = w * 64 + lane;
        gl_lds16(Ks + (size_t)(jn + (L & 31)) * DD + (L >> 5) * 8,
                 kl + (buf ^ 1) * 16384 + w * 1024);
        gl_lds16(VTs + (size_t)(L & 255) * NN + jn + (L >> 8) * 8,
                 vl + (buf ^ 1) * 16384 + w * 1024);
      }
#pragma unroll
      for (int ii = 0; ii < 4; ++ii)
        gl_lds16(crow + jn + 8 * ii, cfl + (buf ^ 1) * 32768 + wave * 4096 + ii * 1024);
    }

    // 3. S^T accumulate from current buffer, two chains for ILP
    const char* klb = kl + buf * 16384;
    const char* vlb = vl + buf * 16384;
    f32x16 sv0, sv1;
#pragma unroll
    for (int r = 0; r < 16; ++r) { sv0[r] = 0.f; sv1[r] = 0.f; }
    __builtin_amdgcn_s_setprio(1);
#pragma unroll
    for (int c = 0; c < 16; c += 2) {
      bf16x8 kf0 = *(const bf16x8*)(klb + (((2 * c + h) * 32 + mm) << 4));
      bf16x8 kf1 = *(const bf16x8*)(klb + (((2 * c + 2 + h) * 32 + mm) << 4));
      sv0 = __builtin_amdgcn_mfma_f32_32x32x16_bf16(kf0, qf[c], sv0, 0, 0, 0);
      sv1 = __builtin_amdgcn_mfma_f32_32x32x16_bf16(kf1, qf[c + 1], sv1, 0, 0, 0);
    }
    __builtin_amdgcn_s_setprio(0);
    f32x16 sv = sv0 + sv1;

    // 4. retire own cf(t) (oldest 4 of 12 outstanding), then read it from LDS
    if (t + 1 < jiters)
      asm volatile("s_waitcnt vmcnt(8)" ::: "memory");
    else
      asm volatile("s_waitcnt vmcnt(0)" ::: "memory");
    float cf[16];
    {
      const char* cfb = cfl + buf * 32768 + wave * 4096 + h * 512 + mm * 16;
#pragma unroll
      for (int g = 0; g < 4; ++g) {
        float4 t4 = *(const float4*)(cfb + g * 1024);
        cf[4 * g + 0] = t4.x;
        cf[4 * g + 1] = t4.y;
        cf[4 * g + 2] = t4.z;
        cf[4 * g + 3] = t4.w;
      }
    }

    // 5. online softmax, defer-max: per-lane state indexed by mm (q-row)
    float ma = fmaxf(fmaxf(sv[0], sv[1]), sv[2]);
    float mb2 = fmaxf(fmaxf(sv[3], sv[4]), sv[5]);
    float mc = fmaxf(fmaxf(sv[6], sv[7]), sv[8]);
    float md = fmaxf(fmaxf(sv[9], sv[10]), sv[11]);
    float me = fmaxf(fmaxf(sv[12], sv[13]), sv[14]);
    float mx = fmaxf(fmaxf(fmaxf(ma, mb2), mc), fmaxf(fmaxf(md, me), sv[15]));
    mx = fmaxf(mx, __shfl_xor(mx, 32));

    const bool upd = __any(mx > m_run + 8.f);  // T13: tolerate growth <= 8
    if (upd) {
      const float m_new = fmaxf(m_run, mx);
      const float alpha = __expf(m_run - m_new);
      l_run *= alpha;
#pragma unroll
      for (int nt = 0; nt < 8; ++nt)
#pragma unroll
        for (int r = 0; r < 16; ++r) acc[nt][r] *= alpha;
      m_run = m_new;
    }
    const float msub = m_run - LN_K;

    float p[16];
#pragma unroll
    for (int r = 0; r < 16; ++r) p[r] = __expf(sv[r] - msub) * cf[r];
    // balanced sum tree (no fast-math reassociation at -O3)
    float s0 = (p[0] + p[1]) + (p[2] + p[3]);
    float s1 = (p[4] + p[5]) + (p[6] + p[7]);
    float s2 = (p[8] + p[9]) + (p[10] + p[11]);
    float s3 = (p[12] + p[13]) + (p[14] + p[15]);
    float bsum = (s0 + s1) + (s2 + s3);
    bsum += __shfl_xor(bsum, 32);
    l_run += bsum;

    // 6. pack P pairs (bf16 trunc; bias cancelled by LN_K scale)
    u32 P2[8];
#pragma unroll
    for (int j = 0; j < 8; ++j) {
      const u32 ua = __float_as_uint(p[2 * j]);
      const u32 ub = __float_as_uint(p[2 * j + 1]);
      P2[j] = (ua >> 16) | (ub & 0xFFFF0000u);
    }
    // 7. PV: O'[n][mm] += V^T[n][jj] * P[jj][mm]
#pragma unroll
    for (int kc2 = 0; kc2 < 2; ++kc2) {
      union { u32 u[4]; bf16x8 v; } pf;
#pragma unroll
      for (int tp = 0; tp < 4; ++tp) {
        const int src = mm + 32 * (tp >> 1);
        const u32 va = __shfl(P2[4 * kc2 + (tp & 1)], src);
        const u32 vb = __shfl(P2[4 * kc2 + 2 + (tp & 1)], src);
        pf.u[tp] = h ? vb : va;
      }
      __builtin_amdgcn_s_setprio(1);
#pragma unroll
      for (int nt = 0; nt < 8; ++nt) {
        bf16x8 vf = *(const bf16x8*)(vlb + ((((2 * kc2 + h) * 256) + nt * 32 + mm) << 4));
        acc[nt] = __builtin_amdgcn_mfma_f32_32x32x16_bf16(vf, pf.v, acc[nt], 0, 0, 0);
      }
      __builtin_amdgcn_s_setprio(0);
    }
    // no end-of-iter barrier: next iter's vmcnt(4)+s_barrier protects reuse
  }

  // partials
  const int wb = rb * 8 + wave;  // 0..255, row = wb*32 + mm (unchanged mapping)
  if (lane < 32) {
    ml[((sp * 256 + wb) << 6) + lane] = m_run;
    ml[((sp * 256 + wb) << 6) + 32 + lane] = l_run;
  }
#pragma unroll
  for (int nt = 0; nt < 8; ++nt) {
#pragma unroll
    for (int rr = 0; rr < 4; ++rr) {
      // lane-major: wave stores 1KB contiguous per (nt,rr)
      float* op = Op + ((((size_t)(sp * 256 + wb) * 8 + nt) * 4 + rr) * 64 + lane) * 4;
      float4 v = make_float4(acc[nt][4 * rr], acc[nt][4 * rr + 1],
                             acc[nt][4 * rr + 2], acc[nt][4 * rr + 3]);
      *(float4*)op = v;
    }
  }
}

// ---------------- kernel 3: merge splits + elu + fp32 out ------------------
// Templated on SPL: runtime-indexed mv/lv/wsc arrays were rule-20 scratch.
template <int SPL>
__global__ __launch_bounds__(256) void merge_out(const float* __restrict__ ml,
                                                 const float* __restrict__ Op,
                                                 float* __restrict__ out) {
  const int wid = blockIdx.x * 4 + (threadIdx.x >> 6);
  const int lane = threadIdx.x & 63, mm = lane & 31, h = lane >> 5;
  const int wb = wid >> 3, nt = wid & 7;
  float mv[SPL], lv[SPL], wsc[SPL];
#pragma unroll
  for (int s = 0; s < SPL; ++s) {
    mv[s] = ml[((s * 256 + wb) << 6) + mm];
    lv[s] = ml[((s * 256 + wb) << 6) + 32 + mm];
  }
  float M = mv[0];
#pragma unroll
  for (int s = 1; s < SPL; ++s) M = fmaxf(M, mv[s]);
  float L = 0.f;
#pragma unroll
  for (int s = 0; s < SPL; ++s) {
    wsc[s] = __expf(mv[s] - M);
    L += wsc[s] * lv[s];
  }
  const float inv = 1.f / (L + 1e-9f);

  float o[16];
#pragma unroll
  for (int r = 0; r < 16; ++r) o[r] = 0.f;
#pragma unroll
  for (int s = 0; s < SPL; ++s) {
#pragma unroll
    for (int rr = 0; rr < 4; ++rr) {
      const float* op = Op + ((((size_t)(s * 256 + wb) * 8 + nt) * 4 + rr) * 64 + lane) * 4;
      float4 v = *(const float4*)op;
      o[4 * rr + 0] += wsc[s] * v.x;
      o[4 * rr + 1] += wsc[s] * v.y;
      o[4 * rr + 2] += wsc[s] * v.z;
      o[4 * rr + 3] += wsc[s] * v.w;
    }
  }
  // out[row][col], col = (r&3) + 8*(r>>2) + 4h: contiguous float4 per g=r>>2
  const int row = wb * 32 + mm;
#pragma unroll
  for (int g = 0; g < 4; ++g) {
    float4 v;
    float* pv = &v.x;
#pragma unroll
    for (int i = 0; i < 4; ++i) {
      float t = o[4 * g + i] * inv;
      pv[i] = t > 0.f ? t : expm1f(t);  // elu, alpha=1
    }
    *(float4*)(out + (size_t)row * DD + nt * 32 + 8 * g + 4 * h) = v;
  }
}

extern "C" void kernel_launch(void* const* d_in, const int* in_sizes, int n_in,
                              void* d_out, int out_size, void* d_ws, size_t ws_size,
                              hipStream_t stream) {
  const float* feat = (const float*)d_in[0];
  const float* cnta = (const float*)d_in[1];
  const float* Wq = (const float*)d_in[2];
  const float* Wk = (const float*)d_in[3];
  const float* Wv = (const float*)d_in[4];
  char* ws = (char*)d_ws;
  u16* WT = (u16*)(ws);                      // 768 KB
  u16* featb = (u16*)(ws + (1ull << 20));    // 8 MB
  u16* Qs = (u16*)(ws + (9ull << 20));       // 4 MB
  u16* Ks = (u16*)(ws + (13ull << 20));      // 4 MB
  u16* VTs = (u16*)(ws + (17ull << 20));     // 4 MB
  float* ml = (float*)(ws + (21ull << 20));  // 1 MB (spl<=8)
  float* Op = (float*)(ws + (22ull << 20));  // spl*8 MB
  float* out = (float*)d_out;

  // spl=8 needs 22MB + 64MB = 86MB of ws; fall back to proven 54MB layout.
  const size_t need8 = (22ull << 20) + (64ull << 20);
  const int spl = (ws_size >= need8) ? 8 : 4;
  const int jiters = NN / (spl * 32);

  // allow 128KB dynamic LDS (gfx950 supports up to 160KB/workgroup)
  static bool attr_set = false;
  if (!attr_set) {
    (void)hipFuncSetAttribute((const void*)flash_attn,
                              hipFuncAttributeMaxDynamicSharedMemorySize, 131072);
    attr_set = true;
  }

  hipLaunchKernelGGL(wt_transpose, dim3(64, 3), dim3(256), 0, stream, Wq, Wk, Wv, WT);
  hipLaunchKernelGGL(cvt_feat, dim3(4096), dim3(256), 0, stream, feat, featb);
  hipLaunchKernelGGL(proj_qkv, dim3(256, 3), dim3(256), 0, stream, featb, WT, Qs, Ks, VTs);
  // 1-D grid: bid % spl == XCD (round-robin); 32*spl blocks of 512 threads
  hipLaunchKernelGGL(flash_attn, dim3(32 * spl), dim3(512), 131072, stream, Qs, Ks, VTs,
                     cnta, ml, Op, jiters, spl);
  if (spl == 8) {
    hipLaunchKernelGGL((merge_out<8>), dim3(512), dim3(256), 0, stream, ml, Op, out);
  } else {
    hipLaunchKernelGGL((merge_out<4>), dim3(512), dim3(256), 0, stream, ml, Op, out);
  }
}